// Round 8
// baseline (175.755 us; speedup 1.0000x reference)
//
#include <hip/hip_runtime.h>
#include <stdint.h>

using u16 = unsigned short;
typedef __attribute__((ext_vector_type(8))) _Float16 half8;
typedef __attribute__((ext_vector_type(4))) float f32x4;
typedef __attribute__((ext_vector_type(4))) unsigned short u16x4;

#define S_LEN 2048
#define D_MODEL 1024
#define NHEAD 16
#define HDIM 64

__device__ __forceinline__ u16 f2h_bits(float f){
    _Float16 h = (_Float16)f;
    return __builtin_bit_cast(u16, h);
}

typedef __attribute__((address_space(1))) void gvoid;
typedef __attribute__((address_space(3))) void lvoid;
__device__ __forceinline__ void gload_lds16(const u16* g, u16* l){
    __builtin_amdgcn_global_load_lds((gvoid*)(uintptr_t)g, (lvoid*)l, 16, 0, 0);
}

// ---------- x fp32 -> fp16 ----------
__global__ __launch_bounds__(256) void k_cvt_x(const float* __restrict__ x, u16* __restrict__ xh){
    int i = blockIdx.x*256 + threadIdx.x;
    float4 v = reinterpret_cast<const float4*>(x)[i];
    u16x4 o;
    o.x = f2h_bits(v.x); o.y = f2h_bits(v.y); o.z = f2h_bits(v.z); o.w = f2h_bits(v.w);
    reinterpret_cast<u16x4*>(xh)[i] = o;
}

// ---------- W [K][N] fp32 -> WT [N][K] fp16 (transpose via LDS) ----------
__global__ __launch_bounds__(256) void k_cvt_wT(const float* __restrict__ W, u16* __restrict__ WT,
                                                int K, int N){
    __shared__ float t[32][33];
    int tx = threadIdx.x & 31, ty = threadIdx.x >> 5;   // 32 x 8
    int n0 = blockIdx.x*32, k0 = blockIdx.y*32;
    #pragma unroll
    for (int i=0;i<4;++i) t[ty+8*i][tx] = W[(size_t)(k0+ty+8*i)*N + n0+tx];
    __syncthreads();
    #pragma unroll
    for (int i=0;i<4;++i) WT[(size_t)(n0+ty+8*i)*K + k0+tx] = f2h_bits(t[tx][ty+8*i]);
}

// ---------- GEMM (m97 structure): 128x128 tile, BK=32, LDS-staged via global_load_lds ----------
template<int EPI>
__global__ __launch_bounds__(256) void k_gemm(const u16* __restrict__ A, const u16* __restrict__ BT,
                                              float* __restrict__ Cf, u16* __restrict__ Qh,
                                              u16* __restrict__ Kh, u16* __restrict__ Vt){
    constexpr int Kd = 1024;
    __shared__ u16 As[128*32];
    __shared__ u16 Bs[128*32];
    int nwg = gridDim.x;
    int cpx = nwg >> 3;
    int wg  = ((int)blockIdx.x & 7)*cpx + ((int)blockIdx.x >> 3);   // XCD-chunked
    int tm = wg & 31, tn = wg >> 5;                                 // m-fastest within chunk
    int t = threadIdx.x;
    int w = t >> 6, lane = t & 63;
    int lr = lane & 15, lg = lane >> 4;
    int wm = (w>>1)*64, wn = (w&1)*64;
    int m0 = tm*128 + wm, n0 = tn*128 + wn;

    const u16* aG = A  + (size_t)(tm*128 + (t>>2))*Kd + (t&3)*8;
    const u16* bG = BT + (size_t)(tn*128 + (t>>2))*Kd + (t&3)*8;
    u16* aL = As + (t>>2)*32 + (t&3)*8;
    u16* bL = Bs + (t>>2)*32 + (t&3)*8;

    f32x4 acc[4][4];
    #pragma unroll
    for (int i=0;i<4;++i)
        #pragma unroll
        for (int j=0;j<4;++j) acc[i][j] = (f32x4){0.f,0.f,0.f,0.f};

    for (int kk=0; kk<Kd; kk+=32){
        gload_lds16(aG + kk, aL);
        gload_lds16(aG + kk + (size_t)64*Kd, aL + 64*32);
        gload_lds16(bG + kk, bL);
        gload_lds16(bG + kk + (size_t)64*Kd, bL + 64*32);
        __syncthreads();

        half8 av[4], bv[4];
        #pragma unroll
        for (int mf=0;mf<4;++mf) av[mf] = *reinterpret_cast<const half8*>(&As[(wm+mf*16+lr)*32 + lg*8]);
        #pragma unroll
        for (int nf=0;nf<4;++nf) bv[nf] = *reinterpret_cast<const half8*>(&Bs[(wn+nf*16+lr)*32 + lg*8]);
        __builtin_amdgcn_s_setprio(1);
        #pragma unroll
        for (int mf=0;mf<4;++mf)
            #pragma unroll
            for (int nf=0;nf<4;++nf)
                acc[mf][nf] = __builtin_amdgcn_mfma_f32_16x16x32_f16(av[mf], bv[nf], acc[mf][nf], 0,0,0);
        __builtin_amdgcn_s_setprio(0);
        __syncthreads();
    }

    if (EPI == 0){
        #pragma unroll
        for (int mf=0;mf<4;++mf)
            #pragma unroll
            for (int nf=0;nf<4;++nf)
                #pragma unroll
                for (int j=0;j<4;++j)
                    Cf[(size_t)(m0+mf*16+lg*4+j)*D_MODEL + n0+nf*16+lr] = acc[mf][nf][j];
    } else {
        #pragma unroll
        for (int mf=0;mf<4;++mf){
            int r0 = m0 + mf*16 + lg*4;
            int b  = r0 >> 11, s = r0 & 2047;
            #pragma unroll
            for (int nf=0;nf<4;++nf){
                int col = n0 + nf*16 + lr;
                int which = col >> 10;
                int d  = col & 1023;
                int h  = d >> 6, di = d & 63;
                int bh = b*NHEAD + h;
                if (which == 2){
                    u16x4 pv;
                    pv.x = f2h_bits(acc[mf][nf][0]);
                    pv.y = f2h_bits(acc[mf][nf][1]);
                    pv.z = f2h_bits(acc[mf][nf][2]);
                    pv.w = f2h_bits(acc[mf][nf][3]);
                    *reinterpret_cast<u16x4*>(Vt + ((size_t)bh*HDIM + di)*S_LEN + s) = pv;
                } else {
                    u16* dst = (which==0 ? Qh : Kh) + ((size_t)bh*S_LEN + s)*HDIM + di;
                    #pragma unroll
                    for (int j=0;j<4;++j) dst[(size_t)j*HDIM] = f2h_bits(acc[mf][nf][j]);
                }
            }
        }
    }
}

// ---------- flash attention v7: CU-balanced zigzag placement ----------
// r7 diagnosis: all 2048 blocks are resident at t=0 (no queue), placement is
// sequential ~8 blocks/CU, and qt in the HIGH bits clustered all qt=63 blocks
// (33 k-tiles each) onto the same CUs -> those CUs carried 2x the average work.
// Fix: zigzag qt in bits {0-2,8-10} so every consecutive-8 group sums to exactly
// 132 k-tiles (e.g. {32,1,32,1,31,2,31,2}); bh in bits 3-7.
// Also dropped the lgkmcnt/sched_barrier pinning: plain-C++ LDS deps are
// compiler-tracked (DS ops are in-order per wave), scheduler is freer.
__global__ __launch_bounds__(64,2) void k_attn(const u16* __restrict__ Q, const u16* __restrict__ K,
                                               const u16* __restrict__ Vt, u16* __restrict__ Mg){
    __shared__ u16 plds[32][72];
    int lane = threadIdx.x;
    int lr = lane & 15, lg = lane >> 4;
    int blk = blockIdx.x;
    int bh  = (blk >> 3) & 31;
    int qti = ((blk >> 8) << 3) | (blk & 7);     // 0..63
    int qt  = (qti & 1) ? (qti >> 1) : 63 - (qti >> 1);   // zigzag: balanced per CU
    int q0  = qt*32;
    int b = bh >> 4, h = bh & 15;
    const u16* Qp = Q  + (size_t)bh*S_LEN*HDIM;
    const u16* Kp = K  + (size_t)bh*S_LEN*HDIM;
    const u16* Vp = Vt + (size_t)bh*HDIM*S_LEN;

    // Q fragments (B-operand), pre-scaled by log2(e)
    half8 qf[2][2];
    #pragma unroll
    for (int qi=0;qi<2;++qi)
        #pragma unroll
        for (int ks=0;ks<2;++ks){
            half8 v = *reinterpret_cast<const half8*>(Qp + (size_t)(q0+qi*16+lr)*HDIM + ks*32 + lg*8);
            #pragma unroll
            for (int j=0;j<8;++j) v[j] = v[j] * (_Float16)1.44269504f;
            qf[qi][ks] = v;
        }

    f32x4 oacc[2][4];
    float mrow[2], lrow[2];
    #pragma unroll
    for (int mf=0;mf<2;++mf){
        #pragma unroll
        for (int nf=0;nf<4;++nf) oacc[mf][nf] = (f32x4){0.f,0.f,0.f,0.f};
        mrow[mf] = -1e30f; lrow[mf] = 0.f;
    }

    int ktiles = (q0 + 32 + 63) >> 6;

    half8 kA[4][2], kB[4][2];
    // prologue: K tile 0 -> kA
    #pragma unroll
    for (int kf=0;kf<4;++kf)
        #pragma unroll
        for (int ks=0;ks<2;++ks)
            kA[kf][ks] = *reinterpret_cast<const half8*>(Kp + (size_t)(kf*16+lr)*HDIM + ks*32 + lg*8);

    auto body = [&](half8 (&kc)[4][2], half8 (&kn)[4][2], int kt){
        int kbase = kt*64;
        // --- prefetch NEXT tile's K into the other buffer ---
        if (kt+1 < ktiles){
            int kbn = (kt+1)*64;
            #pragma unroll
            for (int kf=0;kf<4;++kf)
                #pragma unroll
                for (int ks=0;ks<2;++ks)
                    kn[kf][ks] = *reinterpret_cast<const half8*>(Kp + (size_t)(kbn+kf*16+lr)*HDIM + ks*32 + lg*8);
        }
        // --- S^T = K Q^T : lane holds k = kf*16+lg*4+j, q = qi*16+lr ---
        f32x4 sc[4][2];
        #pragma unroll
        for (int kf=0;kf<4;++kf)
            #pragma unroll
            for (int qi=0;qi<2;++qi) sc[kf][qi] = (f32x4){0.f,0.f,0.f,0.f};
        __builtin_amdgcn_s_setprio(1);
        #pragma unroll
        for (int kf=0;kf<4;++kf)
            #pragma unroll
            for (int qi=0;qi<2;++qi)
                #pragma unroll
                for (int ks=0;ks<2;++ks)
                    sc[kf][qi] = __builtin_amdgcn_mfma_f32_16x16x32_f16(kc[kf][ks], qf[qi][ks], sc[kf][qi], 0,0,0);
        __builtin_amdgcn_s_setprio(0);

        // --- V loads: latency hides under softmax ---
        half8 vf[4][2];
        #pragma unroll
        for (int nf=0;nf<4;++nf)
            #pragma unroll
            for (int kh=0;kh<2;++kh)
                vf[nf][kh] = *reinterpret_cast<const half8*>(Vp + (size_t)(nf*16+lr)*S_LEN + kbase + kh*32 + lg*8);

        if (kt == ktiles-1){                     // causal mask on tail tile
            #pragma unroll
            for (int kf=0;kf<4;++kf)
                #pragma unroll
                for (int qi=0;qi<2;++qi)
                    #pragma unroll
                    for (int j=0;j<4;++j)
                        if (kbase+kf*16+lg*4+j > q0+qi*16+lr) sc[kf][qi][j] = -1e9f;
        }

        // --- row max: in-reg + 2 shuffles per q-frag ---
        float pmax[2];
        #pragma unroll
        for (int qi=0;qi<2;++qi){
            float t0 = fmaxf(fmaxf(sc[0][qi][0], sc[0][qi][1]), fmaxf(sc[0][qi][2], sc[0][qi][3]));
            float t1 = fmaxf(fmaxf(sc[1][qi][0], sc[1][qi][1]), fmaxf(sc[1][qi][2], sc[1][qi][3]));
            float t2 = fmaxf(fmaxf(sc[2][qi][0], sc[2][qi][1]), fmaxf(sc[2][qi][2], sc[2][qi][3]));
            float t3 = fmaxf(fmaxf(sc[3][qi][0], sc[3][qi][1]), fmaxf(sc[3][qi][2], sc[3][qi][3]));
            float tm = fmaxf(fmaxf(t0,t1), fmaxf(t2,t3));
            tm = fmaxf(tm, __shfl_xor(tm,16));
            tm = fmaxf(tm, __shfl_xor(tm,32));
            pmax[qi] = tm;
        }
        // --- defer-rescale (THR=8 in log2 domain) ---
        bool need = (pmax[0] > mrow[0]+8.0f) || (pmax[1] > mrow[1]+8.0f);
        if (__any(need)){
            float aq[2];
            #pragma unroll
            for (int qi=0;qi<2;++qi){
                float mnew = fmaxf(mrow[qi], pmax[qi]);
                aq[qi] = __builtin_amdgcn_exp2f(mrow[qi] - mnew);
                mrow[qi] = mnew;
                lrow[qi] *= aq[qi];
            }
            float am[2][4];
            #pragma unroll
            for (int mf=0;mf<2;++mf)
                #pragma unroll
                for (int j=0;j<4;++j) am[mf][j] = __shfl(aq[mf], lg*4+j);
            #pragma unroll
            for (int mf=0;mf<2;++mf)
                #pragma unroll
                for (int nf=0;nf<4;++nf)
                    #pragma unroll
                    for (int j=0;j<4;++j) oacc[mf][nf][j] *= am[mf][j];
        }
        // --- P = exp2(s - m), row sum in-register ---
        #pragma unroll
        for (int qi=0;qi<2;++qi){
            float m = mrow[qi];
            float rs = 0.f;
            #pragma unroll
            for (int kf=0;kf<4;++kf)
                #pragma unroll
                for (int j=0;j<4;++j){
                    float e = __builtin_amdgcn_exp2f(sc[kf][qi][j] - m);
                    sc[kf][qi][j] = e;
                    rs += e;
                }
            rs += __shfl_xor(rs,16);
            rs += __shfl_xor(rs,32);
            lrow[qi] += rs;
        }
        // --- P -> LDS: k-contiguous j-regs pack to u16x4, 8x ds_write_b64 ---
        #pragma unroll
        for (int kf=0;kf<4;++kf)
            #pragma unroll
            for (int qi=0;qi<2;++qi){
                u16x4 pk;
                pk.x = f2h_bits(sc[kf][qi][0]);
                pk.y = f2h_bits(sc[kf][qi][1]);
                pk.z = f2h_bits(sc[kf][qi][2]);
                pk.w = f2h_bits(sc[kf][qi][3]);
                *reinterpret_cast<u16x4*>(&plds[qi*16+lr][kf*16+lg*4]) = pk;
            }
        // (plain C++ deps: compiler inserts the lgkmcnt; DS ops are in-order per wave)
        half8 pa[2][2];
        #pragma unroll
        for (int mf=0;mf<2;++mf)
            #pragma unroll
            for (int kh=0;kh<2;++kh)
                pa[mf][kh] = *reinterpret_cast<const half8*>(&plds[mf*16+lr][kh*32 + lg*8]);
        __builtin_amdgcn_s_setprio(1);
        #pragma unroll
        for (int mf=0;mf<2;++mf)
            #pragma unroll
            for (int nf=0;nf<4;++nf)
                #pragma unroll
                for (int kh=0;kh<2;++kh)
                    oacc[mf][nf] = __builtin_amdgcn_mfma_f32_16x16x32_f16(pa[mf][kh], vf[nf][kh], oacc[mf][nf], 0,0,0);
        __builtin_amdgcn_s_setprio(0);
    };

    int kt = 0;
    for (; kt+1 < ktiles; kt += 2){
        body(kA, kB, kt);
        body(kB, kA, kt+1);
    }
    if (kt < ktiles) body(kA, kB, kt);

    // epilogue: redistribute 1/l to oacc row layout
    float linv[2][4];
    #pragma unroll
    for (int mf=0;mf<2;++mf)
        #pragma unroll
        for (int j=0;j<4;++j) linv[mf][j] = 1.0f/__shfl(lrow[mf], lg*4+j);
    #pragma unroll
    for (int mf=0;mf<2;++mf)
        #pragma unroll
        for (int nf=0;nf<4;++nf)
            #pragma unroll
            for (int j=0;j<4;++j)
                Mg[(size_t)(b*S_LEN + q0 + mf*16 + lg*4 + j)*D_MODEL + h*HDIM + nf*16 + lr]
                    = f2h_bits(oacc[mf][nf][j]*linv[mf][j]);
}

extern "C" void kernel_launch(void* const* d_in, const int* in_sizes, int n_in,
                              void* d_out, int out_size, void* d_ws, size_t ws_size,
                              hipStream_t stream) {
    const float* x    = (const float*)d_in[0];
    const float* wqkv = (const float*)d_in[1];
    const float* wout = (const float*)d_in[2];
    float* out = (float*)d_out;
    char* ws = (char*)d_ws;

    const size_t MB = 1u<<20;
    u16* xh     = (u16*)(ws + 0*MB);
    u16* wqkvT  = (u16*)(ws + 8*MB);
    u16* woutT  = (u16*)(ws + 14*MB);
    u16* Qh     = (u16*)(ws + 16*MB);
    u16* Kh     = (u16*)(ws + 24*MB);
    u16* Vt     = (u16*)(ws + 32*MB);
    u16* Mg     = (u16*)(ws + 40*MB);

    k_cvt_x <<<4096, 256, 0, stream>>>(x, xh);
    k_cvt_wT<<<dim3(96,32), 256, 0, stream>>>(wqkv, wqkvT, 1024, 3072);
    k_cvt_wT<<<dim3(32,32), 256, 0, stream>>>(wout, woutT, 1024, 1024);
    k_gemm<1><<<768, 256, 0, stream>>>(xh, wqkvT, nullptr, Qh, Kh, Vt);
    k_attn  <<<2048, 64, 0, stream>>>(Qh, Kh, Vt, Mg);
    k_gemm<0><<<256, 256, 0, stream>>>(Mg, woutT, out, nullptr, nullptr, nullptr);
}

// Round 9
// 134.111 us; speedup vs baseline: 1.3105x; 1.3105x over previous
//
#include <hip/hip_runtime.h>
#include <stdint.h>

using u16 = unsigned short;
typedef __attribute__((ext_vector_type(8))) _Float16 half8;
typedef __attribute__((ext_vector_type(4))) float f32x4;
typedef __attribute__((ext_vector_type(4))) unsigned short u16x4;

#define S_LEN 2048
#define D_MODEL 1024
#define NHEAD 16
#define HDIM 64

__device__ __forceinline__ u16 f2h_bits(float f){
    _Float16 h = (_Float16)f;
    return __builtin_bit_cast(u16, h);
}

typedef __attribute__((address_space(1))) void gvoid;
typedef __attribute__((address_space(3))) void lvoid;
__device__ __forceinline__ void gload_lds16(const u16* g, u16* l){
    __builtin_amdgcn_global_load_lds((gvoid*)(uintptr_t)g, (lvoid*)l, 16, 0, 0);
}

// ---------- x fp32 -> fp16 ----------
__global__ __launch_bounds__(256) void k_cvt_x(const float* __restrict__ x, u16* __restrict__ xh){
    int i = blockIdx.x*256 + threadIdx.x;
    float4 v = reinterpret_cast<const float4*>(x)[i];
    u16x4 o;
    o.x = f2h_bits(v.x); o.y = f2h_bits(v.y); o.z = f2h_bits(v.z); o.w = f2h_bits(v.w);
    reinterpret_cast<u16x4*>(xh)[i] = o;
}

// ---------- W [K][N] fp32 -> WT [N][K] fp16 (transpose via LDS) ----------
__global__ __launch_bounds__(256) void k_cvt_wT(const float* __restrict__ W, u16* __restrict__ WT,
                                                int K, int N){
    __shared__ float t[32][33];
    int tx = threadIdx.x & 31, ty = threadIdx.x >> 5;   // 32 x 8
    int n0 = blockIdx.x*32, k0 = blockIdx.y*32;
    #pragma unroll
    for (int i=0;i<4;++i) t[ty+8*i][tx] = W[(size_t)(k0+ty+8*i)*N + n0+tx];
    __syncthreads();
    #pragma unroll
    for (int i=0;i<4;++i) WT[(size_t)(n0+ty+8*i)*K + k0+tx] = f2h_bits(t[tx][ty+8*i]);
}

// ---------- GEMM (m97 structure): 128x128 tile, BK=32, LDS-staged via global_load_lds ----------
template<int EPI>
__global__ __launch_bounds__(256) void k_gemm(const u16* __restrict__ A, const u16* __restrict__ BT,
                                              float* __restrict__ Cf, u16* __restrict__ Qh,
                                              u16* __restrict__ Kh, u16* __restrict__ Vt){
    constexpr int Kd = 1024;
    __shared__ u16 As[128*32];
    __shared__ u16 Bs[128*32];
    int nwg = gridDim.x;
    int cpx = nwg >> 3;
    int wg  = ((int)blockIdx.x & 7)*cpx + ((int)blockIdx.x >> 3);   // XCD-chunked
    int tm = wg & 31, tn = wg >> 5;                                 // m-fastest within chunk
    int t = threadIdx.x;
    int w = t >> 6, lane = t & 63;
    int lr = lane & 15, lg = lane >> 4;
    int wm = (w>>1)*64, wn = (w&1)*64;
    int m0 = tm*128 + wm, n0 = tn*128 + wn;

    const u16* aG = A  + (size_t)(tm*128 + (t>>2))*Kd + (t&3)*8;
    const u16* bG = BT + (size_t)(tn*128 + (t>>2))*Kd + (t&3)*8;
    u16* aL = As + (t>>2)*32 + (t&3)*8;
    u16* bL = Bs + (t>>2)*32 + (t&3)*8;

    f32x4 acc[4][4];
    #pragma unroll
    for (int i=0;i<4;++i)
        #pragma unroll
        for (int j=0;j<4;++j) acc[i][j] = (f32x4){0.f,0.f,0.f,0.f};

    for (int kk=0; kk<Kd; kk+=32){
        gload_lds16(aG + kk, aL);
        gload_lds16(aG + kk + (size_t)64*Kd, aL + 64*32);
        gload_lds16(bG + kk, bL);
        gload_lds16(bG + kk + (size_t)64*Kd, bL + 64*32);
        __syncthreads();

        half8 av[4], bv[4];
        #pragma unroll
        for (int mf=0;mf<4;++mf) av[mf] = *reinterpret_cast<const half8*>(&As[(wm+mf*16+lr)*32 + lg*8]);
        #pragma unroll
        for (int nf=0;nf<4;++nf) bv[nf] = *reinterpret_cast<const half8*>(&Bs[(wn+nf*16+lr)*32 + lg*8]);
        __builtin_amdgcn_s_setprio(1);
        #pragma unroll
        for (int mf=0;mf<4;++mf)
            #pragma unroll
            for (int nf=0;nf<4;++nf)
                acc[mf][nf] = __builtin_amdgcn_mfma_f32_16x16x32_f16(av[mf], bv[nf], acc[mf][nf], 0,0,0);
        __builtin_amdgcn_s_setprio(0);
        __syncthreads();
    }

    if (EPI == 0){
        #pragma unroll
        for (int mf=0;mf<4;++mf)
            #pragma unroll
            for (int nf=0;nf<4;++nf)
                #pragma unroll
                for (int j=0;j<4;++j)
                    Cf[(size_t)(m0+mf*16+lg*4+j)*D_MODEL + n0+nf*16+lr] = acc[mf][nf][j];
    } else {
        #pragma unroll
        for (int mf=0;mf<4;++mf){
            int r0 = m0 + mf*16 + lg*4;
            int b  = r0 >> 11, s = r0 & 2047;
            #pragma unroll
            for (int nf=0;nf<4;++nf){
                int col = n0 + nf*16 + lr;
                int which = col >> 10;
                int d  = col & 1023;
                int h  = d >> 6, di = d & 63;
                int bh = b*NHEAD + h;
                if (which == 2){
                    u16x4 pv;
                    pv.x = f2h_bits(acc[mf][nf][0]);
                    pv.y = f2h_bits(acc[mf][nf][1]);
                    pv.z = f2h_bits(acc[mf][nf][2]);
                    pv.w = f2h_bits(acc[mf][nf][3]);
                    *reinterpret_cast<u16x4*>(Vt + ((size_t)bh*HDIM + di)*S_LEN + s) = pv;
                } else {
                    u16* dst = (which==0 ? Qh : Kh) + ((size_t)bh*S_LEN + s)*HDIM + di;
                    #pragma unroll
                    for (int j=0;j<4;++j) dst[(size_t)j*HDIM] = f2h_bits(acc[mf][nf][j]);
                }
            }
        }
    }
}

// ---------- flash attention v8: 4-wave blocks, shared K/V tile in LDS (m97-style) ----------
// r8 lessons: (1) bh->XCD L2 pinning is worth ~25us (FETCH 12->69MB when lost) -> restore
// bh = blk&31. (2) dispatch is round-robin, placement balance comes from pairing qb in the
// HIGH bits: g=blk>>5, qb = g<8 ? g : 23-g -> CU pair (g,g+8) sums to exactly 34 k-tiles.
// Core change: K/V 64x64 tile staged ONCE per block into LDS (global_load_lds, 4 instr/thr),
// amortized across 4 waves; reads are ~120cyc LDS not 200-400cyc L2. XOR-swizzle (T2) with
// linear LDS dest + inverse-swizzled GLOBAL source + swizzled read (rule #21): chunk c holds
// global chunk (c&7)^((c>>3)&7) of row c>>3 -> read byte ^= (row&7)<<4 -> 2-way conflicts (free).
// Waves skip fully-masked tiles (kt<=lastkt) but always hit both barriers.
__global__ __launch_bounds__(256,3) void k_attn(const u16* __restrict__ Q, const u16* __restrict__ K,
                                                const u16* __restrict__ Vt, u16* __restrict__ Mg){
    __shared__ u16 Kl[64*64];
    __shared__ u16 Vl[64*64];
    __shared__ u16 plds[4][32][72];
    int t = threadIdx.x;
    int w = t >> 6, lane = t & 63;
    int lr = lane & 15, lg = lane >> 4;
    int blk = blockIdx.x;
    int bh  = blk & 31;                      // XCD = blk%8 = bh%8: 4 bh/XCD, 2MB K+V in L2
    int g   = blk >> 5;                      // 0..15
    int qb  = (g < 8) ? g : 23 - g;          // pair (g,g+8): ktb 2qb+2 sums to 34
    int q0w = qb*128 + w*32;                 // this wave's 32 q-rows
    int b = bh >> 4, h = bh & 15;
    const u16* Qp = Q  + (size_t)bh*S_LEN*HDIM;
    const u16* Kp = K  + (size_t)bh*S_LEN*HDIM;
    const u16* Vp = Vt + (size_t)bh*HDIM*S_LEN;

    // staging: 512 16B-chunks (64 rows x 8), 2 per thread; source column pre-swizzled
    int c0 = t, c1 = t + 256;
    int r0 = c0 >> 3, s0 = 8*((c0 & 7) ^ (r0 & 7));
    int r1 = c1 >> 3, s1 = 8*((c1 & 7) ^ (r1 & 7));
    const u16* Ks0 = Kp + (size_t)r0*HDIM + s0;
    const u16* Ks1 = Kp + (size_t)r1*HDIM + s1;
    const u16* Vs0 = Vp + (size_t)r0*S_LEN + s0;
    const u16* Vs1 = Vp + (size_t)r1*S_LEN + s1;
    u16* Kd0 = Kl + c0*8; u16* Kd1 = Kl + c1*8;
    u16* Vd0 = Vl + c0*8; u16* Vd1 = Vl + c1*8;

    // Q fragments (B-operand), pre-scaled by log2(e)
    half8 qf[2][2];
    #pragma unroll
    for (int qi=0;qi<2;++qi)
        #pragma unroll
        for (int ks=0;ks<2;++ks){
            half8 v = *reinterpret_cast<const half8*>(Qp + (size_t)(q0w+qi*16+lr)*HDIM + ks*32 + lg*8);
            #pragma unroll
            for (int j=0;j<8;++j) v[j] = v[j] * (_Float16)1.44269504f;
            qf[qi][ks] = v;
        }

    f32x4 oacc[2][4];
    float mrow[2], lrow[2];
    #pragma unroll
    for (int mf=0;mf<2;++mf){
        #pragma unroll
        for (int nf=0;nf<4;++nf) oacc[mf][nf] = (f32x4){0.f,0.f,0.f,0.f};
        mrow[mf] = -1e30f; lrow[mf] = 0.f;
    }

    int ktb    = 2*qb + 2;
    int lastkt = (q0w + 31) >> 6;            // wave's last (diagonal) tile

    int swz = (lr & 7)*8;                    // read-side XOR (u16 units)

    for (int kt=0; kt<ktb; ++kt){
        int kbase = kt*64;
        gload_lds16(Ks0 + (size_t)kbase*HDIM, Kd0);
        gload_lds16(Ks1 + (size_t)kbase*HDIM, Kd1);
        gload_lds16(Vs0 + kbase, Vd0);
        gload_lds16(Vs1 + kbase, Vd1);
        __syncthreads();                     // compiler drains vmcnt: tile staged + all waves here

        if (kt <= lastkt){
            // --- K fragments from LDS (swizzled) ---
            half8 kfr[4][2];
            #pragma unroll
            for (int kf=0;kf<4;++kf)
                #pragma unroll
                for (int ks=0;ks<2;++ks)
                    kfr[kf][ks] = *reinterpret_cast<const half8*>(Kl + (kf*16+lr)*64 + ((ks*32 + lg*8) ^ swz));
            // --- S^T = K Q^T ---
            f32x4 sc[4][2];
            #pragma unroll
            for (int kf=0;kf<4;++kf)
                #pragma unroll
                for (int qi=0;qi<2;++qi) sc[kf][qi] = (f32x4){0.f,0.f,0.f,0.f};
            __builtin_amdgcn_s_setprio(1);
            #pragma unroll
            for (int kf=0;kf<4;++kf)
                #pragma unroll
                for (int qi=0;qi<2;++qi)
                    #pragma unroll
                    for (int ks=0;ks<2;++ks)
                        sc[kf][qi] = __builtin_amdgcn_mfma_f32_16x16x32_f16(kfr[kf][ks], qf[qi][ks], sc[kf][qi], 0,0,0);
            __builtin_amdgcn_s_setprio(0);

            // --- V fragments issued early (LDS latency hides under softmax) ---
            half8 vf[4][2];
            #pragma unroll
            for (int nf=0;nf<4;++nf)
                #pragma unroll
                for (int kh=0;kh<2;++kh)
                    vf[nf][kh] = *reinterpret_cast<const half8*>(Vl + (nf*16+lr)*64 + ((kh*32 + lg*8) ^ swz));

            if (kt == lastkt){               // causal mask on diagonal tile
                #pragma unroll
                for (int kf=0;kf<4;++kf)
                    #pragma unroll
                    for (int qi=0;qi<2;++qi)
                        #pragma unroll
                        for (int j=0;j<4;++j)
                            if (kbase+kf*16+lg*4+j > q0w+qi*16+lr) sc[kf][qi][j] = -1e9f;
            }

            // --- row max ---
            float pmax[2];
            #pragma unroll
            for (int qi=0;qi<2;++qi){
                float t0 = fmaxf(fmaxf(sc[0][qi][0], sc[0][qi][1]), fmaxf(sc[0][qi][2], sc[0][qi][3]));
                float t1 = fmaxf(fmaxf(sc[1][qi][0], sc[1][qi][1]), fmaxf(sc[1][qi][2], sc[1][qi][3]));
                float t2 = fmaxf(fmaxf(sc[2][qi][0], sc[2][qi][1]), fmaxf(sc[2][qi][2], sc[2][qi][3]));
                float t3 = fmaxf(fmaxf(sc[3][qi][0], sc[3][qi][1]), fmaxf(sc[3][qi][2], sc[3][qi][3]));
                float tm = fmaxf(fmaxf(t0,t1), fmaxf(t2,t3));
                tm = fmaxf(tm, __shfl_xor(tm,16));
                tm = fmaxf(tm, __shfl_xor(tm,32));
                pmax[qi] = tm;
            }
            // --- defer-rescale (THR=8 in log2 domain) ---
            bool need = (pmax[0] > mrow[0]+8.0f) || (pmax[1] > mrow[1]+8.0f);
            if (__any(need)){
                float aq[2];
                #pragma unroll
                for (int qi=0;qi<2;++qi){
                    float mnew = fmaxf(mrow[qi], pmax[qi]);
                    aq[qi] = __builtin_amdgcn_exp2f(mrow[qi] - mnew);
                    mrow[qi] = mnew;
                    lrow[qi] *= aq[qi];
                }
                float am[2][4];
                #pragma unroll
                for (int mf=0;mf<2;++mf)
                    #pragma unroll
                    for (int j=0;j<4;++j) am[mf][j] = __shfl(aq[mf], lg*4+j);
                #pragma unroll
                for (int mf=0;mf<2;++mf)
                    #pragma unroll
                    for (int nf=0;nf<4;++nf)
                        #pragma unroll
                        for (int j=0;j<4;++j) oacc[mf][nf][j] *= am[mf][j];
            }
            // --- P = exp2(s - m), row sum ---
            #pragma unroll
            for (int qi=0;qi<2;++qi){
                float m = mrow[qi];
                float rs = 0.f;
                #pragma unroll
                for (int kf=0;kf<4;++kf)
                    #pragma unroll
                    for (int j=0;j<4;++j){
                        float e = __builtin_amdgcn_exp2f(sc[kf][qi][j] - m);
                        sc[kf][qi][j] = e;
                        rs += e;
                    }
                rs += __shfl_xor(rs,16);
                rs += __shfl_xor(rs,32);
                lrow[qi] += rs;
            }
            // --- P -> per-wave LDS tile ---
            #pragma unroll
            for (int kf=0;kf<4;++kf)
                #pragma unroll
                for (int qi=0;qi<2;++qi){
                    u16x4 pk;
                    pk.x = f2h_bits(sc[kf][qi][0]);
                    pk.y = f2h_bits(sc[kf][qi][1]);
                    pk.z = f2h_bits(sc[kf][qi][2]);
                    pk.w = f2h_bits(sc[kf][qi][3]);
                    *reinterpret_cast<u16x4*>(&plds[w][qi*16+lr][kf*16+lg*4]) = pk;
                }
            half8 pa[2][2];
            #pragma unroll
            for (int mf=0;mf<2;++mf)
                #pragma unroll
                for (int kh=0;kh<2;++kh)
                    pa[mf][kh] = *reinterpret_cast<const half8*>(&plds[w][mf*16+lr][kh*32 + lg*8]);
            __builtin_amdgcn_s_setprio(1);
            #pragma unroll
            for (int mf=0;mf<2;++mf)
                #pragma unroll
                for (int nf=0;nf<4;++nf)
                    #pragma unroll
                    for (int kh=0;kh<2;++kh)
                        oacc[mf][nf] = __builtin_amdgcn_mfma_f32_16x16x32_f16(pa[mf][kh], vf[nf][kh], oacc[mf][nf], 0,0,0);
            __builtin_amdgcn_s_setprio(0);
        }
        __syncthreads();                     // all waves done reading Kl/Vl before next stage
    }

    // epilogue
    float linv[2][4];
    #pragma unroll
    for (int mf=0;mf<2;++mf)
        #pragma unroll
        for (int j=0;j<4;++j) linv[mf][j] = 1.0f/__shfl(lrow[mf], lg*4+j);
    #pragma unroll
    for (int mf=0;mf<2;++mf)
        #pragma unroll
        for (int nf=0;nf<4;++nf)
            #pragma unroll
            for (int j=0;j<4;++j)
                Mg[(size_t)(b*S_LEN + q0w + mf*16 + lg*4 + j)*D_MODEL + h*HDIM + nf*16 + lr]
                    = f2h_bits(oacc[mf][nf][j]*linv[mf][j]);
}

extern "C" void kernel_launch(void* const* d_in, const int* in_sizes, int n_in,
                              void* d_out, int out_size, void* d_ws, size_t ws_size,
                              hipStream_t stream) {
    const float* x    = (const float*)d_in[0];
    const float* wqkv = (const float*)d_in[1];
    const float* wout = (const float*)d_in[2];
    float* out = (float*)d_out;
    char* ws = (char*)d_ws;

    const size_t MB = 1u<<20;
    u16* xh     = (u16*)(ws + 0*MB);
    u16* wqkvT  = (u16*)(ws + 8*MB);
    u16* woutT  = (u16*)(ws + 14*MB);
    u16* Qh     = (u16*)(ws + 16*MB);
    u16* Kh     = (u16*)(ws + 24*MB);
    u16* Vt     = (u16*)(ws + 32*MB);
    u16* Mg     = (u16*)(ws + 40*MB);

    k_cvt_x <<<4096, 256, 0, stream>>>(x, xh);
    k_cvt_wT<<<dim3(96,32), 256, 0, stream>>>(wqkv, wqkvT, 1024, 3072);
    k_cvt_wT<<<dim3(32,32), 256, 0, stream>>>(wout, woutT, 1024, 1024);
    k_gemm<1><<<768, 256, 0, stream>>>(xh, wqkvT, nullptr, Qh, Kh, Vt);
    k_attn  <<<512, 256, 0, stream>>>(Qh, Kh, Vt, Mg);
    k_gemm<0><<<256, 256, 0, stream>>>(Mg, woutT, out, nullptr, nullptr, nullptr);
}

// Round 10
// 129.454 us; speedup vs baseline: 1.3577x; 1.0360x over previous
//
#include <hip/hip_runtime.h>
#include <stdint.h>

using u16 = unsigned short;
typedef __attribute__((ext_vector_type(8))) _Float16 half8;
typedef __attribute__((ext_vector_type(4))) float f32x4;
typedef __attribute__((ext_vector_type(4))) unsigned short u16x4;

#define S_LEN 2048
#define D_MODEL 1024
#define NHEAD 16
#define HDIM 64

__device__ __forceinline__ u16 f2h_bits(float f){
    _Float16 h = (_Float16)f;
    return __builtin_bit_cast(u16, h);
}
__device__ __forceinline__ float h2f_bits(u16 v){
    return (float)__builtin_bit_cast(_Float16, v);
}

typedef __attribute__((address_space(1))) void gvoid;
typedef __attribute__((address_space(3))) void lvoid;
__device__ __forceinline__ void gload_lds16(const u16* g, u16* l){
    __builtin_amdgcn_global_load_lds((gvoid*)(uintptr_t)g, (lvoid*)l, 16, 0, 0);
}

// ---------- x fp32 -> fp16 ----------
__global__ __launch_bounds__(256) void k_cvt_x(const float* __restrict__ x, u16* __restrict__ xh){
    int i = blockIdx.x*256 + threadIdx.x;
    float4 v = reinterpret_cast<const float4*>(x)[i];
    u16x4 o;
    o.x = f2h_bits(v.x); o.y = f2h_bits(v.y); o.z = f2h_bits(v.z); o.w = f2h_bits(v.w);
    reinterpret_cast<u16x4*>(xh)[i] = o;
}

// ---------- W [K][N] fp32 -> WT [N][K] fp16 (transpose via LDS) ----------
__global__ __launch_bounds__(256) void k_cvt_wT(const float* __restrict__ W, u16* __restrict__ WT,
                                                int K, int N){
    __shared__ float t[32][33];
    int tx = threadIdx.x & 31, ty = threadIdx.x >> 5;   // 32 x 8
    int n0 = blockIdx.x*32, k0 = blockIdx.y*32;
    #pragma unroll
    for (int i=0;i<4;++i) t[ty+8*i][tx] = W[(size_t)(k0+ty+8*i)*N + n0+tx];
    __syncthreads();
    #pragma unroll
    for (int i=0;i<4;++i) WT[(size_t)(n0+ty+8*i)*K + k0+tx] = f2h_bits(t[tx][ty+8*i]);
}

// ---------- GEMM (m97 structure): 128x128 tile, BK=32, LDS-staged via global_load_lds ----------
template<int EPI>
__global__ __launch_bounds__(256) void k_gemm(const u16* __restrict__ A, const u16* __restrict__ BT,
                                              float* __restrict__ Cf, u16* __restrict__ Qh,
                                              u16* __restrict__ Kh, u16* __restrict__ Vt){
    constexpr int Kd = 1024;
    __shared__ u16 As[128*32];
    __shared__ u16 Bs[128*32];
    int nwg = gridDim.x;
    int cpx = nwg >> 3;
    int wg  = ((int)blockIdx.x & 7)*cpx + ((int)blockIdx.x >> 3);   // XCD-chunked
    int tm = wg & 31, tn = wg >> 5;                                 // m-fastest within chunk
    int t = threadIdx.x;
    int w = t >> 6, lane = t & 63;
    int lr = lane & 15, lg = lane >> 4;
    int wm = (w>>1)*64, wn = (w&1)*64;
    int m0 = tm*128 + wm, n0 = tn*128 + wn;

    const u16* aG = A  + (size_t)(tm*128 + (t>>2))*Kd + (t&3)*8;
    const u16* bG = BT + (size_t)(tn*128 + (t>>2))*Kd + (t&3)*8;
    u16* aL = As + (t>>2)*32 + (t&3)*8;
    u16* bL = Bs + (t>>2)*32 + (t&3)*8;

    f32x4 acc[4][4];
    #pragma unroll
    for (int i=0;i<4;++i)
        #pragma unroll
        for (int j=0;j<4;++j) acc[i][j] = (f32x4){0.f,0.f,0.f,0.f};

    for (int kk=0; kk<Kd; kk+=32){
        gload_lds16(aG + kk, aL);
        gload_lds16(aG + kk + (size_t)64*Kd, aL + 64*32);
        gload_lds16(bG + kk, bL);
        gload_lds16(bG + kk + (size_t)64*Kd, bL + 64*32);
        __syncthreads();

        half8 av[4], bv[4];
        #pragma unroll
        for (int mf=0;mf<4;++mf) av[mf] = *reinterpret_cast<const half8*>(&As[(wm+mf*16+lr)*32 + lg*8]);
        #pragma unroll
        for (int nf=0;nf<4;++nf) bv[nf] = *reinterpret_cast<const half8*>(&Bs[(wn+nf*16+lr)*32 + lg*8]);
        __builtin_amdgcn_s_setprio(1);
        #pragma unroll
        for (int mf=0;mf<4;++mf)
            #pragma unroll
            for (int nf=0;nf<4;++nf)
                acc[mf][nf] = __builtin_amdgcn_mfma_f32_16x16x32_f16(av[mf], bv[nf], acc[mf][nf], 0,0,0);
        __builtin_amdgcn_s_setprio(0);
        __syncthreads();
    }

    if (EPI == 0){
        #pragma unroll
        for (int mf=0;mf<4;++mf)
            #pragma unroll
            for (int nf=0;nf<4;++nf)
                #pragma unroll
                for (int j=0;j<4;++j)
                    Cf[(size_t)(m0+mf*16+lg*4+j)*D_MODEL + n0+nf*16+lr] = acc[mf][nf][j];
    } else {
        #pragma unroll
        for (int mf=0;mf<4;++mf){
            int r0 = m0 + mf*16 + lg*4;
            int b  = r0 >> 11, s = r0 & 2047;
            #pragma unroll
            for (int nf=0;nf<4;++nf){
                int col = n0 + nf*16 + lr;
                int which = col >> 10;
                int d  = col & 1023;
                int h  = d >> 6, di = d & 63;
                int bh = b*NHEAD + h;
                if (which == 2){
                    u16x4 pv;
                    pv.x = f2h_bits(acc[mf][nf][0]);
                    pv.y = f2h_bits(acc[mf][nf][1]);
                    pv.z = f2h_bits(acc[mf][nf][2]);
                    pv.w = f2h_bits(acc[mf][nf][3]);
                    *reinterpret_cast<u16x4*>(Vt + ((size_t)bh*HDIM + di)*S_LEN + s) = pv;
                } else {
                    u16* dst = (which==0 ? Qh : Kh) + ((size_t)bh*S_LEN + s)*HDIM + di;
                    #pragma unroll
                    for (int j=0;j<4;++j) dst[(size_t)j*HDIM] = f2h_bits(acc[mf][nf][j]);
                }
            }
        }
    }
}

// ---------- flash attention v9: flash-decode split, max 16-tile serial path ----------
// r9 lesson: pairing equalized per-CU TOTALS but the heavy block still had a 32-tile
// serial path and ran alone (occupancy 11.6%). Fix: split qb>=8 into two k-range parts
// (<=16 tiles each); 24 blocks/bh = 768 blocks = 3/CU = 12 waves/CU. p-order
// [2,4..16 | 16,15..9 | 16,15..9] makes round-robin CU triples {p,p+8,p+16} sum to 34.
// Split parts write normalized-O(fp16)+m,l(f32) partials; k_comb merges (one 2-way
// online-softmax merge per row). Block internals identical to r9.
__global__ __launch_bounds__(256,3) void k_attn(const u16* __restrict__ Q, const u16* __restrict__ K,
                                                const u16* __restrict__ Vt, u16* __restrict__ Mg,
                                                u16* __restrict__ On, float* __restrict__ Ml,
                                                float* __restrict__ Ll){
    __shared__ u16 Kl[64*64];
    __shared__ u16 Vl[64*64];
    __shared__ u16 plds[4][32][72];
    int t = threadIdx.x;
    int w = t >> 6, lane = t & 63;
    int lr = lane & 15, lg = lane >> 4;
    int blk = blockIdx.x;
    int bh  = blk & 31;                      // XCD = bh%8: K/V L2-pinned
    int p   = blk >> 5;                      // 0..23
    int qb, ktLo, ktHi, part; bool split;
    if (p < 8)      { qb = p;    ktLo = 0;      ktHi = 2*p+2;   split = false; part = 0; }
    else if (p < 16){ qb = 23-p; ktLo = 0;      ktHi = qb+1;    split = true;  part = 0; }
    else            { qb = 31-p; ktLo = qb+1;   ktHi = 2*qb+2;  split = true;  part = 1; }
    int q0w = qb*128 + w*32;                 // this wave's 32 q-rows
    int b = bh >> 4, h = bh & 15;
    int pid = split ? ((bh<<3) + (qb-8))*2 + part : 0;
    const u16* Qp = Q  + (size_t)bh*S_LEN*HDIM;
    const u16* Kp = K  + (size_t)bh*S_LEN*HDIM;
    const u16* Vp = Vt + (size_t)bh*HDIM*S_LEN;

    // staging: 512 16B-chunks, 2/thread; source column pre-swizzled (rule #21)
    int c0 = t, c1 = t + 256;
    int r0 = c0 >> 3, s0 = 8*((c0 & 7) ^ (r0 & 7));
    int r1 = c1 >> 3, s1 = 8*((c1 & 7) ^ (r1 & 7));
    const u16* Ks0 = Kp + (size_t)r0*HDIM + s0;
    const u16* Ks1 = Kp + (size_t)r1*HDIM + s1;
    const u16* Vs0 = Vp + (size_t)r0*S_LEN + s0;
    const u16* Vs1 = Vp + (size_t)r1*S_LEN + s1;
    u16* Kd0 = Kl + c0*8; u16* Kd1 = Kl + c1*8;
    u16* Vd0 = Vl + c0*8; u16* Vd1 = Vl + c1*8;

    // Q fragments (B-operand), pre-scaled by log2(e)
    half8 qf[2][2];
    #pragma unroll
    for (int qi=0;qi<2;++qi)
        #pragma unroll
        for (int ks=0;ks<2;++ks){
            half8 v = *reinterpret_cast<const half8*>(Qp + (size_t)(q0w+qi*16+lr)*HDIM + ks*32 + lg*8);
            #pragma unroll
            for (int j=0;j<8;++j) v[j] = v[j] * (_Float16)1.44269504f;
            qf[qi][ks] = v;
        }

    f32x4 oacc[2][4];
    float mrow[2], lrow[2];
    #pragma unroll
    for (int mf=0;mf<2;++mf){
        #pragma unroll
        for (int nf=0;nf<4;++nf) oacc[mf][nf] = (f32x4){0.f,0.f,0.f,0.f};
        mrow[mf] = -1e30f; lrow[mf] = 0.f;
    }

    int lastkt = (q0w + 31) >> 6;            // wave's diagonal tile
    int swz = (lr & 7)*8;                    // read-side XOR (u16 units)

    for (int kt=ktLo; kt<ktHi; ++kt){
        int kbase = kt*64;
        gload_lds16(Ks0 + (size_t)kbase*HDIM, Kd0);
        gload_lds16(Ks1 + (size_t)kbase*HDIM, Kd1);
        gload_lds16(Vs0 + kbase, Vd0);
        gload_lds16(Vs1 + kbase, Vd1);
        __syncthreads();

        if (kt <= lastkt){
            half8 kfr[4][2];
            #pragma unroll
            for (int kf=0;kf<4;++kf)
                #pragma unroll
                for (int ks=0;ks<2;++ks)
                    kfr[kf][ks] = *reinterpret_cast<const half8*>(Kl + (kf*16+lr)*64 + ((ks*32 + lg*8) ^ swz));
            f32x4 sc[4][2];
            #pragma unroll
            for (int kf=0;kf<4;++kf)
                #pragma unroll
                for (int qi=0;qi<2;++qi) sc[kf][qi] = (f32x4){0.f,0.f,0.f,0.f};
            __builtin_amdgcn_s_setprio(1);
            #pragma unroll
            for (int kf=0;kf<4;++kf)
                #pragma unroll
                for (int qi=0;qi<2;++qi)
                    #pragma unroll
                    for (int ks=0;ks<2;++ks)
                        sc[kf][qi] = __builtin_amdgcn_mfma_f32_16x16x32_f16(kfr[kf][ks], qf[qi][ks], sc[kf][qi], 0,0,0);
            __builtin_amdgcn_s_setprio(0);

            half8 vf[4][2];
            #pragma unroll
            for (int nf=0;nf<4;++nf)
                #pragma unroll
                for (int kh=0;kh<2;++kh)
                    vf[nf][kh] = *reinterpret_cast<const half8*>(Vl + (nf*16+lr)*64 + ((kh*32 + lg*8) ^ swz));

            if (kt == lastkt){               // causal mask (unreachable for split part0)
                #pragma unroll
                for (int kf=0;kf<4;++kf)
                    #pragma unroll
                    for (int qi=0;qi<2;++qi)
                        #pragma unroll
                        for (int j=0;j<4;++j)
                            if (kbase+kf*16+lg*4+j > q0w+qi*16+lr) sc[kf][qi][j] = -1e9f;
            }

            float pmax[2];
            #pragma unroll
            for (int qi=0;qi<2;++qi){
                float t0 = fmaxf(fmaxf(sc[0][qi][0], sc[0][qi][1]), fmaxf(sc[0][qi][2], sc[0][qi][3]));
                float t1 = fmaxf(fmaxf(sc[1][qi][0], sc[1][qi][1]), fmaxf(sc[1][qi][2], sc[1][qi][3]));
                float t2 = fmaxf(fmaxf(sc[2][qi][0], sc[2][qi][1]), fmaxf(sc[2][qi][2], sc[2][qi][3]));
                float t3 = fmaxf(fmaxf(sc[3][qi][0], sc[3][qi][1]), fmaxf(sc[3][qi][2], sc[3][qi][3]));
                float tm = fmaxf(fmaxf(t0,t1), fmaxf(t2,t3));
                tm = fmaxf(tm, __shfl_xor(tm,16));
                tm = fmaxf(tm, __shfl_xor(tm,32));
                pmax[qi] = tm;
            }
            bool need = (pmax[0] > mrow[0]+8.0f) || (pmax[1] > mrow[1]+8.0f);
            if (__any(need)){
                float aq[2];
                #pragma unroll
                for (int qi=0;qi<2;++qi){
                    float mnew = fmaxf(mrow[qi], pmax[qi]);
                    aq[qi] = __builtin_amdgcn_exp2f(mrow[qi] - mnew);
                    mrow[qi] = mnew;
                    lrow[qi] *= aq[qi];
                }
                float am[2][4];
                #pragma unroll
                for (int mf=0;mf<2;++mf)
                    #pragma unroll
                    for (int j=0;j<4;++j) am[mf][j] = __shfl(aq[mf], lg*4+j);
                #pragma unroll
                for (int mf=0;mf<2;++mf)
                    #pragma unroll
                    for (int nf=0;nf<4;++nf)
                        #pragma unroll
                        for (int j=0;j<4;++j) oacc[mf][nf][j] *= am[mf][j];
            }
            #pragma unroll
            for (int qi=0;qi<2;++qi){
                float m = mrow[qi];
                float rs = 0.f;
                #pragma unroll
                for (int kf=0;kf<4;++kf)
                    #pragma unroll
                    for (int j=0;j<4;++j){
                        float e = __builtin_amdgcn_exp2f(sc[kf][qi][j] - m);
                        sc[kf][qi][j] = e;
                        rs += e;
                    }
                rs += __shfl_xor(rs,16);
                rs += __shfl_xor(rs,32);
                lrow[qi] += rs;
            }
            #pragma unroll
            for (int kf=0;kf<4;++kf)
                #pragma unroll
                for (int qi=0;qi<2;++qi){
                    u16x4 pk;
                    pk.x = f2h_bits(sc[kf][qi][0]);
                    pk.y = f2h_bits(sc[kf][qi][1]);
                    pk.z = f2h_bits(sc[kf][qi][2]);
                    pk.w = f2h_bits(sc[kf][qi][3]);
                    *reinterpret_cast<u16x4*>(&plds[w][qi*16+lr][kf*16+lg*4]) = pk;
                }
            half8 pa[2][2];
            #pragma unroll
            for (int mf=0;mf<2;++mf)
                #pragma unroll
                for (int kh=0;kh<2;++kh)
                    pa[mf][kh] = *reinterpret_cast<const half8*>(&plds[w][mf*16+lr][kh*32 + lg*8]);
            __builtin_amdgcn_s_setprio(1);
            #pragma unroll
            for (int mf=0;mf<2;++mf)
                #pragma unroll
                for (int nf=0;nf<4;++nf)
                    #pragma unroll
                    for (int kh=0;kh<2;++kh)
                        oacc[mf][nf] = __builtin_amdgcn_mfma_f32_16x16x32_f16(pa[mf][kh], vf[nf][kh], oacc[mf][nf], 0,0,0);
            __builtin_amdgcn_s_setprio(0);
        }
        __syncthreads();
    }

    // epilogue: normalize; write Mg (single) or partial (split)
    float linv[2][4];
    #pragma unroll
    for (int mf=0;mf<2;++mf)
        #pragma unroll
        for (int j=0;j<4;++j) linv[mf][j] = 1.0f/__shfl(lrow[mf], lg*4+j);
    if (!split){
        #pragma unroll
        for (int mf=0;mf<2;++mf)
            #pragma unroll
            for (int nf=0;nf<4;++nf)
                #pragma unroll
                for (int j=0;j<4;++j)
                    Mg[(size_t)(b*S_LEN + q0w + mf*16 + lg*4 + j)*D_MODEL + h*HDIM + nf*16 + lr]
                        = f2h_bits(oacc[mf][nf][j]*linv[mf][j]);
    } else {
        #pragma unroll
        for (int mf=0;mf<2;++mf)
            #pragma unroll
            for (int nf=0;nf<4;++nf)
                #pragma unroll
                for (int j=0;j<4;++j)
                    On[pid*8192 + (w*32 + mf*16 + lg*4 + j)*64 + nf*16 + lr]
                        = f2h_bits(oacc[mf][nf][j]*linv[mf][j]);
        if (lg == 0){
            #pragma unroll
            for (int qi=0;qi<2;++qi){
                Ml[pid*128 + w*32 + qi*16 + lr] = mrow[qi];
                Ll[pid*128 + w*32 + qi*16 + lr] = lrow[qi];
            }
        }
    }
}

// ---------- partial merge: one 2-way online-softmax merge per split q-tile ----------
__global__ __launch_bounds__(256) void k_comb(const u16* __restrict__ On, const float* __restrict__ Ml,
                                              const float* __restrict__ Ll, u16* __restrict__ Mg){
    int blk = blockIdx.x;
    int bh = blk & 31;                       // XCD-matched with producer
    int q8 = blk >> 5;                       // 0..7 -> qb = 8+q8
    int qb = 8 + q8;
    int b = bh >> 4, h = bh & 15;
    int t = threadIdx.x;
    int c = t & 63, rg = t >> 6;             // 4 row-groups x 32 rows
    int pid0 = ((bh<<3) + q8)*2, pid1 = pid0 + 1;
    #pragma unroll 4
    for (int i=0;i<32;++i){
        int r = rg*32 + i;
        float m1 = Ml[pid0*128 + r], m2 = Ml[pid1*128 + r];
        float l1 = Ll[pid0*128 + r], l2 = Ll[pid1*128 + r];
        float M  = fmaxf(m1, m2);
        float w1 = l1*__builtin_amdgcn_exp2f(m1 - M);
        float w2 = l2*__builtin_amdgcn_exp2f(m2 - M);
        float o1 = h2f_bits(On[pid0*8192 + r*64 + c]);
        float o2 = h2f_bits(On[pid1*8192 + r*64 + c]);
        float o  = (w1*o1 + w2*o2) / (w1 + w2);
        Mg[(size_t)(b*S_LEN + qb*128 + r)*D_MODEL + h*HDIM + c] = f2h_bits(o);
    }
}

extern "C" void kernel_launch(void* const* d_in, const int* in_sizes, int n_in,
                              void* d_out, int out_size, void* d_ws, size_t ws_size,
                              hipStream_t stream) {
    const float* x    = (const float*)d_in[0];
    const float* wqkv = (const float*)d_in[1];
    const float* wout = (const float*)d_in[2];
    float* out = (float*)d_out;
    char* ws = (char*)d_ws;

    const size_t MB = 1u<<20;
    u16* xh     = (u16*)(ws + 0*MB);
    u16* wqkvT  = (u16*)(ws + 8*MB);
    u16* woutT  = (u16*)(ws + 14*MB);
    u16* Qh     = (u16*)(ws + 16*MB);
    u16* Kh     = (u16*)(ws + 24*MB);
    u16* Vt     = (u16*)(ws + 32*MB);
    u16* Mg     = (u16*)(ws + 40*MB);
    u16* On     = (u16*)(ws + 48*MB);        // [512][128][64] fp16 normalized O partials (8MB)
    float* Ml   = (float*)(ws + 56*MB);      // [512][128] f32 (256KB)
    float* Ll   = (float*)(ws + 56*MB + 256*1024);

    k_cvt_x <<<4096, 256, 0, stream>>>(x, xh);
    k_cvt_wT<<<dim3(96,32), 256, 0, stream>>>(wqkv, wqkvT, 1024, 3072);
    k_cvt_wT<<<dim3(32,32), 256, 0, stream>>>(wout, woutT, 1024, 1024);
    k_gemm<1><<<768, 256, 0, stream>>>(xh, wqkvT, nullptr, Qh, Kh, Vt);
    k_attn  <<<768, 256, 0, stream>>>(Qh, Kh, Vt, Mg, On, Ml, Ll);
    k_comb  <<<256, 256, 0, stream>>>(On, Ml, Ll, Mg);
    k_gemm<0><<<256, 256, 0, stream>>>(Mg, woutT, out, nullptr, nullptr, nullptr);
}

// Round 11
// 119.580 us; speedup vs baseline: 1.4698x; 1.0826x over previous
//
#include <hip/hip_runtime.h>
#include <stdint.h>

using u16 = unsigned short;
typedef __attribute__((ext_vector_type(8))) _Float16 half8;
typedef __attribute__((ext_vector_type(4))) float f32x4;
typedef __attribute__((ext_vector_type(4))) unsigned short u16x4;

#define S_LEN 2048
#define D_MODEL 1024
#define NHEAD 16
#define HDIM 64

__device__ __forceinline__ u16 f2h_bits(float f){
    _Float16 h = (_Float16)f;
    return __builtin_bit_cast(u16, h);
}
__device__ __forceinline__ float h2f_bits(u16 v){
    return (float)__builtin_bit_cast(_Float16, v);
}

typedef __attribute__((address_space(1))) void gvoid;
typedef __attribute__((address_space(3))) void lvoid;
__device__ __forceinline__ void gload_lds16(const u16* g, u16* l){
    __builtin_amdgcn_global_load_lds((gvoid*)(uintptr_t)g, (lvoid*)l, 16, 0, 0);
}

// ---------- x fp32 -> fp16 ----------
__global__ __launch_bounds__(256) void k_cvt_x(const float* __restrict__ x, u16* __restrict__ xh){
    int i = blockIdx.x*256 + threadIdx.x;
    float4 v = reinterpret_cast<const float4*>(x)[i];
    u16x4 o;
    o.x = f2h_bits(v.x); o.y = f2h_bits(v.y); o.z = f2h_bits(v.z); o.w = f2h_bits(v.w);
    reinterpret_cast<u16x4*>(xh)[i] = o;
}

// ---------- both weights [K][N] fp32 -> [N][K] fp16 in ONE launch ----------
// grid (128, 32): x<96 -> wqkv (N=3072), else wout (N=1024). K=1024 both.
__global__ __launch_bounds__(256) void k_cvt_w(const float* __restrict__ W0, u16* __restrict__ T0,
                                               const float* __restrict__ W1, u16* __restrict__ T1){
    __shared__ float tt[32][33];
    int bx = blockIdx.x;
    const float* W; u16* WT; int N, n0;
    if (bx < 96){ W = W0; WT = T0; N = 3072; n0 = bx*32; }
    else        { W = W1; WT = T1; N = 1024; n0 = (bx-96)*32; }
    int k0 = blockIdx.y*32;
    int tx = threadIdx.x & 31, ty = threadIdx.x >> 5;   // 32 x 8
    #pragma unroll
    for (int i=0;i<4;++i) tt[ty+8*i][tx] = W[(size_t)(k0+ty+8*i)*N + n0+tx];
    __syncthreads();
    #pragma unroll
    for (int i=0;i<4;++i) WT[(size_t)(n0+ty+8*i)*1024 + k0+tx] = f2h_bits(tt[tx][ty+8*i]);
}

// ---------- GEMM: 128x128 tile, BK=32, double-buffered LDS, ONE barrier per K-step ----------
// r10 change: stage(kt+1) issues at top of step kt's compute; __syncthreads (vmcnt drain)
// finds loads already landed under ~16 MFMA + ds_reads. Helps most at 1 block/CU (out-proj).
template<int EPI>
__global__ __launch_bounds__(256) void k_gemm(const u16* __restrict__ A, const u16* __restrict__ BT,
                                              float* __restrict__ Cf, u16* __restrict__ Qh,
                                              u16* __restrict__ Kh, u16* __restrict__ Vt){
    constexpr int Kd = 1024;
    __shared__ u16 As[2*128*32];
    __shared__ u16 Bs[2*128*32];
    int nwg = gridDim.x;
    int cpx = nwg >> 3;
    int wg  = ((int)blockIdx.x & 7)*cpx + ((int)blockIdx.x >> 3);   // XCD-chunked
    int tm = wg & 31, tn = wg >> 5;                                 // m-fastest within chunk
    int t = threadIdx.x;
    int w = t >> 6, lane = t & 63;
    int lr = lane & 15, lg = lane >> 4;
    int wm = (w>>1)*64, wn = (w&1)*64;
    int m0 = tm*128 + wm, n0 = tn*128 + wn;

    const u16* aG = A  + (size_t)(tm*128 + (t>>2))*Kd + (t&3)*8;
    const u16* bG = BT + (size_t)(tn*128 + (t>>2))*Kd + (t&3)*8;
    u16* aL = As + (t>>2)*32 + (t&3)*8;
    u16* bL = Bs + (t>>2)*32 + (t&3)*8;

    auto stage = [&](int buf, int kk){
        gload_lds16(aG + kk, aL + buf*4096);
        gload_lds16(aG + kk + (size_t)64*Kd, aL + buf*4096 + 64*32);
        gload_lds16(bG + kk, bL + buf*4096);
        gload_lds16(bG + kk + (size_t)64*Kd, bL + buf*4096 + 64*32);
    };

    f32x4 acc[4][4];
    #pragma unroll
    for (int i=0;i<4;++i)
        #pragma unroll
        for (int j=0;j<4;++j) acc[i][j] = (f32x4){0.f,0.f,0.f,0.f};

    stage(0, 0);
    __syncthreads();
    for (int kk=0; kk<Kd; kk+=32){
        int cur = (kk>>5) & 1;
        if (kk+32 < Kd) stage(cur^1, kk+32);

        half8 av[4], bv[4];
        #pragma unroll
        for (int mf=0;mf<4;++mf) av[mf] = *reinterpret_cast<const half8*>(&As[cur*4096 + (wm+mf*16+lr)*32 + lg*8]);
        #pragma unroll
        for (int nf=0;nf<4;++nf) bv[nf] = *reinterpret_cast<const half8*>(&Bs[cur*4096 + (wn+nf*16+lr)*32 + lg*8]);
        __builtin_amdgcn_s_setprio(1);
        #pragma unroll
        for (int mf=0;mf<4;++mf)
            #pragma unroll
            for (int nf=0;nf<4;++nf)
                acc[mf][nf] = __builtin_amdgcn_mfma_f32_16x16x32_f16(av[mf], bv[nf], acc[mf][nf], 0,0,0);
        __builtin_amdgcn_s_setprio(0);
        __syncthreads();   // stage(kt+1) landed under compute; buf[cur] free for overwrite next step
    }

    if (EPI == 0){
        #pragma unroll
        for (int mf=0;mf<4;++mf)
            #pragma unroll
            for (int nf=0;nf<4;++nf)
                #pragma unroll
                for (int j=0;j<4;++j)
                    Cf[(size_t)(m0+mf*16+lg*4+j)*D_MODEL + n0+nf*16+lr] = acc[mf][nf][j];
    } else {
        #pragma unroll
        for (int mf=0;mf<4;++mf){
            int r0 = m0 + mf*16 + lg*4;
            int b  = r0 >> 11, s = r0 & 2047;
            #pragma unroll
            for (int nf=0;nf<4;++nf){
                int col = n0 + nf*16 + lr;
                int which = col >> 10;
                int d  = col & 1023;
                int h  = d >> 6, di = d & 63;
                int bh = b*NHEAD + h;
                if (which == 2){
                    u16x4 pv;
                    pv.x = f2h_bits(acc[mf][nf][0]);
                    pv.y = f2h_bits(acc[mf][nf][1]);
                    pv.z = f2h_bits(acc[mf][nf][2]);
                    pv.w = f2h_bits(acc[mf][nf][3]);
                    *reinterpret_cast<u16x4*>(Vt + ((size_t)bh*HDIM + di)*S_LEN + s) = pv;
                } else {
                    u16* dst = (which==0 ? Qh : Kh) + ((size_t)bh*S_LEN + s)*HDIM + di;
                    #pragma unroll
                    for (int j=0;j<4;++j) dst[(size_t)j*HDIM] = f2h_bits(acc[mf][nf][j]);
                }
            }
        }
    }
}

// ---------- flash attention v10: r9/r10 structure + double-buffered K/V staging ----------
// r10 residual: per tile, stage -> barrier exposed ~500cyc L2 latency with ALL waves
// stalled, 2 barriers/tile. Now: Kl/Vl are [2] buffers; stage(kt+1) issues at top of
// tile kt's compute; ONE __syncthreads per tile (its vmcnt-drain lands under ~2K cyc
// of softmax+MFMA). LDS 51KB -> still 3 blocks/CU = grid exactly.
__global__ __launch_bounds__(256,3) void k_attn(const u16* __restrict__ Q, const u16* __restrict__ K,
                                                const u16* __restrict__ Vt, u16* __restrict__ Mg,
                                                u16* __restrict__ On, float* __restrict__ Ml,
                                                float* __restrict__ Ll){
    __shared__ u16 Kl[2*64*64];
    __shared__ u16 Vl[2*64*64];
    __shared__ u16 plds[4][32][72];
    int t = threadIdx.x;
    int w = t >> 6, lane = t & 63;
    int lr = lane & 15, lg = lane >> 4;
    int blk = blockIdx.x;
    int bh  = blk & 31;                      // XCD = bh%8: K/V L2-pinned
    int p   = blk >> 5;                      // 0..23
    int qb, ktLo, ktHi, part; bool split;
    if (p < 8)      { qb = p;    ktLo = 0;      ktHi = 2*p+2;   split = false; part = 0; }
    else if (p < 16){ qb = 23-p; ktLo = 0;      ktHi = qb+1;    split = true;  part = 0; }
    else            { qb = 31-p; ktLo = qb+1;   ktHi = 2*qb+2;  split = true;  part = 1; }
    int q0w = qb*128 + w*32;                 // this wave's 32 q-rows
    int b = bh >> 4, h = bh & 15;
    int pid = split ? ((bh<<3) + (qb-8))*2 + part : 0;
    const u16* Qp = Q  + (size_t)bh*S_LEN*HDIM;
    const u16* Kp = K  + (size_t)bh*S_LEN*HDIM;
    const u16* Vp = Vt + (size_t)bh*HDIM*S_LEN;

    // staging: 512 16B-chunks, 2/thread; source column pre-swizzled (rule #21)
    int c0 = t, c1 = t + 256;
    int r0 = c0 >> 3, s0 = 8*((c0 & 7) ^ (r0 & 7));
    int r1 = c1 >> 3, s1 = 8*((c1 & 7) ^ (r1 & 7));
    const u16* Ks0 = Kp + (size_t)r0*HDIM + s0;
    const u16* Ks1 = Kp + (size_t)r1*HDIM + s1;
    const u16* Vs0 = Vp + (size_t)r0*S_LEN + s0;
    const u16* Vs1 = Vp + (size_t)r1*S_LEN + s1;
    u16* Kd0 = Kl + c0*8; u16* Kd1 = Kl + c1*8;
    u16* Vd0 = Vl + c0*8; u16* Vd1 = Vl + c1*8;

    auto stageKV = [&](int buf, int kt){
        int kbase = kt*64;
        gload_lds16(Ks0 + (size_t)kbase*HDIM, Kd0 + buf*4096);
        gload_lds16(Ks1 + (size_t)kbase*HDIM, Kd1 + buf*4096);
        gload_lds16(Vs0 + kbase, Vd0 + buf*4096);
        gload_lds16(Vs1 + kbase, Vd1 + buf*4096);
    };

    // Q fragments (B-operand), pre-scaled by log2(e)
    half8 qf[2][2];
    #pragma unroll
    for (int qi=0;qi<2;++qi)
        #pragma unroll
        for (int ks=0;ks<2;++ks){
            half8 v = *reinterpret_cast<const half8*>(Qp + (size_t)(q0w+qi*16+lr)*HDIM + ks*32 + lg*8);
            #pragma unroll
            for (int j=0;j<8;++j) v[j] = v[j] * (_Float16)1.44269504f;
            qf[qi][ks] = v;
        }

    f32x4 oacc[2][4];
    float mrow[2], lrow[2];
    #pragma unroll
    for (int mf=0;mf<2;++mf){
        #pragma unroll
        for (int nf=0;nf<4;++nf) oacc[mf][nf] = (f32x4){0.f,0.f,0.f,0.f};
        mrow[mf] = -1e30f; lrow[mf] = 0.f;
    }

    int lastkt = (q0w + 31) >> 6;            // wave's diagonal tile
    int swz = (lr & 7)*8;                    // read-side XOR (u16 units)
    int nT = ktHi - ktLo;

    stageKV(0, ktLo);
    __syncthreads();
    for (int i=0; i<nT; ++i){
        int kt = ktLo + i;
        int cur = i & 1;
        if (i+1 < nT) stageKV(cur^1, kt+1);  // in flight across this tile's compute

        if (kt <= lastkt){
            const u16* Kb = Kl + cur*4096;
            const u16* Vb = Vl + cur*4096;
            int kbase = kt*64;
            half8 kfr[4][2];
            #pragma unroll
            for (int kf=0;kf<4;++kf)
                #pragma unroll
                for (int ks=0;ks<2;++ks)
                    kfr[kf][ks] = *reinterpret_cast<const half8*>(Kb + (kf*16+lr)*64 + ((ks*32 + lg*8) ^ swz));
            f32x4 sc[4][2];
            #pragma unroll
            for (int kf=0;kf<4;++kf)
                #pragma unroll
                for (int qi=0;qi<2;++qi) sc[kf][qi] = (f32x4){0.f,0.f,0.f,0.f};
            __builtin_amdgcn_s_setprio(1);
            #pragma unroll
            for (int kf=0;kf<4;++kf)
                #pragma unroll
                for (int qi=0;qi<2;++qi)
                    #pragma unroll
                    for (int ks=0;ks<2;++ks)
                        sc[kf][qi] = __builtin_amdgcn_mfma_f32_16x16x32_f16(kfr[kf][ks], qf[qi][ks], sc[kf][qi], 0,0,0);
            __builtin_amdgcn_s_setprio(0);

            half8 vf[4][2];
            #pragma unroll
            for (int nf=0;nf<4;++nf)
                #pragma unroll
                for (int kh=0;kh<2;++kh)
                    vf[nf][kh] = *reinterpret_cast<const half8*>(Vb + (nf*16+lr)*64 + ((kh*32 + lg*8) ^ swz));

            if (kt == lastkt){               // causal mask (unreachable for split part0)
                #pragma unroll
                for (int kf=0;kf<4;++kf)
                    #pragma unroll
                    for (int qi=0;qi<2;++qi)
                        #pragma unroll
                        for (int j=0;j<4;++j)
                            if (kbase+kf*16+lg*4+j > q0w+qi*16+lr) sc[kf][qi][j] = -1e9f;
            }

            float pmax[2];
            #pragma unroll
            for (int qi=0;qi<2;++qi){
                float t0 = fmaxf(fmaxf(sc[0][qi][0], sc[0][qi][1]), fmaxf(sc[0][qi][2], sc[0][qi][3]));
                float t1 = fmaxf(fmaxf(sc[1][qi][0], sc[1][qi][1]), fmaxf(sc[1][qi][2], sc[1][qi][3]));
                float t2 = fmaxf(fmaxf(sc[2][qi][0], sc[2][qi][1]), fmaxf(sc[2][qi][2], sc[2][qi][3]));
                float t3 = fmaxf(fmaxf(sc[3][qi][0], sc[3][qi][1]), fmaxf(sc[3][qi][2], sc[3][qi][3]));
                float tm = fmaxf(fmaxf(t0,t1), fmaxf(t2,t3));
                tm = fmaxf(tm, __shfl_xor(tm,16));
                tm = fmaxf(tm, __shfl_xor(tm,32));
                pmax[qi] = tm;
            }
            bool need = (pmax[0] > mrow[0]+8.0f) || (pmax[1] > mrow[1]+8.0f);
            if (__any(need)){
                float aq[2];
                #pragma unroll
                for (int qi=0;qi<2;++qi){
                    float mnew = fmaxf(mrow[qi], pmax[qi]);
                    aq[qi] = __builtin_amdgcn_exp2f(mrow[qi] - mnew);
                    mrow[qi] = mnew;
                    lrow[qi] *= aq[qi];
                }
                float am[2][4];
                #pragma unroll
                for (int mf=0;mf<2;++mf)
                    #pragma unroll
                    for (int j=0;j<4;++j) am[mf][j] = __shfl(aq[mf], lg*4+j);
                #pragma unroll
                for (int mf=0;mf<2;++mf)
                    #pragma unroll
                    for (int nf=0;nf<4;++nf)
                        #pragma unroll
                        for (int j=0;j<4;++j) oacc[mf][nf][j] *= am[mf][j];
            }
            #pragma unroll
            for (int qi=0;qi<2;++qi){
                float m = mrow[qi];
                float rs = 0.f;
                #pragma unroll
                for (int kf=0;kf<4;++kf)
                    #pragma unroll
                    for (int j=0;j<4;++j){
                        float e = __builtin_amdgcn_exp2f(sc[kf][qi][j] - m);
                        sc[kf][qi][j] = e;
                        rs += e;
                    }
                rs += __shfl_xor(rs,16);
                rs += __shfl_xor(rs,32);
                lrow[qi] += rs;
            }
            #pragma unroll
            for (int kf=0;kf<4;++kf)
                #pragma unroll
                for (int qi=0;qi<2;++qi){
                    u16x4 pk;
                    pk.x = f2h_bits(sc[kf][qi][0]);
                    pk.y = f2h_bits(sc[kf][qi][1]);
                    pk.z = f2h_bits(sc[kf][qi][2]);
                    pk.w = f2h_bits(sc[kf][qi][3]);
                    *reinterpret_cast<u16x4*>(&plds[w][qi*16+lr][kf*16+lg*4]) = pk;
                }
            half8 pa[2][2];
            #pragma unroll
            for (int mf=0;mf<2;++mf)
                #pragma unroll
                for (int kh=0;kh<2;++kh)
                    pa[mf][kh] = *reinterpret_cast<const half8*>(&plds[w][mf*16+lr][kh*32 + lg*8]);
            __builtin_amdgcn_s_setprio(1);
            #pragma unroll
            for (int mf=0;mf<2;++mf)
                #pragma unroll
                for (int nf=0;nf<4;++nf)
                    #pragma unroll
                    for (int kh=0;kh<2;++kh)
                        oacc[mf][nf] = __builtin_amdgcn_mfma_f32_16x16x32_f16(pa[mf][kh], vf[nf][kh], oacc[mf][nf], 0,0,0);
            __builtin_amdgcn_s_setprio(0);
        }
        __syncthreads();   // next stage landed + everyone done with buf[cur]
    }

    // epilogue: normalize; write Mg (single) or partial (split)
    float linv[2][4];
    #pragma unroll
    for (int mf=0;mf<2;++mf)
        #pragma unroll
        for (int j=0;j<4;++j) linv[mf][j] = 1.0f/__shfl(lrow[mf], lg*4+j);
    if (!split){
        #pragma unroll
        for (int mf=0;mf<2;++mf)
            #pragma unroll
            for (int nf=0;nf<4;++nf)
                #pragma unroll
                for (int j=0;j<4;++j)
                    Mg[(size_t)(b*S_LEN + q0w + mf*16 + lg*4 + j)*D_MODEL + h*HDIM + nf*16 + lr]
                        = f2h_bits(oacc[mf][nf][j]*linv[mf][j]);
    } else {
        #pragma unroll
        for (int mf=0;mf<2;++mf)
            #pragma unroll
            for (int nf=0;nf<4;++nf)
                #pragma unroll
                for (int j=0;j<4;++j)
                    On[pid*8192 + (w*32 + mf*16 + lg*4 + j)*64 + nf*16 + lr]
                        = f2h_bits(oacc[mf][nf][j]*linv[mf][j]);
        if (lg == 0){
            #pragma unroll
            for (int qi=0;qi<2;++qi){
                Ml[pid*128 + w*32 + qi*16 + lr] = mrow[qi];
                Ll[pid*128 + w*32 + qi*16 + lr] = lrow[qi];
            }
        }
    }
}

// ---------- partial merge: one 2-way online-softmax merge per split q-tile ----------
__global__ __launch_bounds__(256) void k_comb(const u16* __restrict__ On, const float* __restrict__ Ml,
                                              const float* __restrict__ Ll, u16* __restrict__ Mg){
    int blk = blockIdx.x;
    int bh = blk & 31;                       // XCD-matched with producer
    int q8 = blk >> 5;                       // 0..7 -> qb = 8+q8
    int qb = 8 + q8;
    int b = bh >> 4, h = bh & 15;
    int t = threadIdx.x;
    int c = t & 63, rg = t >> 6;             // 4 row-groups x 32 rows
    int pid0 = ((bh<<3) + q8)*2, pid1 = pid0 + 1;
    #pragma unroll 4
    for (int i=0;i<32;++i){
        int r = rg*32 + i;
        float m1 = Ml[pid0*128 + r], m2 = Ml[pid1*128 + r];
        float l1 = Ll[pid0*128 + r], l2 = Ll[pid1*128 + r];
        float M  = fmaxf(m1, m2);
        float w1 = l1*__builtin_amdgcn_exp2f(m1 - M);
        float w2 = l2*__builtin_amdgcn_exp2f(m2 - M);
        float o1 = h2f_bits(On[pid0*8192 + r*64 + c]);
        float o2 = h2f_bits(On[pid1*8192 + r*64 + c]);
        float o  = (w1*o1 + w2*o2) / (w1 + w2);
        Mg[(size_t)(b*S_LEN + qb*128 + r)*D_MODEL + h*HDIM + c] = f2h_bits(o);
    }
}

extern "C" void kernel_launch(void* const* d_in, const int* in_sizes, int n_in,
                              void* d_out, int out_size, void* d_ws, size_t ws_size,
                              hipStream_t stream) {
    const float* x    = (const float*)d_in[0];
    const float* wqkv = (const float*)d_in[1];
    const float* wout = (const float*)d_in[2];
    float* out = (float*)d_out;
    char* ws = (char*)d_ws;

    const size_t MB = 1u<<20;
    u16* xh     = (u16*)(ws + 0*MB);
    u16* wqkvT  = (u16*)(ws + 8*MB);
    u16* woutT  = (u16*)(ws + 14*MB);
    u16* Qh     = (u16*)(ws + 16*MB);
    u16* Kh     = (u16*)(ws + 24*MB);
    u16* Vt     = (u16*)(ws + 32*MB);
    u16* Mg     = (u16*)(ws + 40*MB);
    u16* On     = (u16*)(ws + 48*MB);        // [512][128][64] fp16 normalized O partials (8MB)
    float* Ml   = (float*)(ws + 56*MB);      // [512][128] f32 (256KB)
    float* Ll   = (float*)(ws + 56*MB + 256*1024);

    k_cvt_x <<<4096, 256, 0, stream>>>(x, xh);
    k_cvt_w <<<dim3(128,32), 256, 0, stream>>>(wqkv, wqkvT, wout, woutT);
    k_gemm<1><<<768, 256, 0, stream>>>(xh, wqkvT, nullptr, Qh, Kh, Vt);
    k_attn  <<<768, 256, 0, stream>>>(Qh, Kh, Vt, Mg, On, Ml, Ll);
    k_comb  <<<256, 256, 0, stream>>>(On, Ml, Ll, Mg);
    k_gemm<0><<<256, 256, 0, stream>>>(Mg, woutT, out, nullptr, nullptr, nullptr);
}